// Round 15
// baseline (90.778 us; speedup 1.0000x reference)
//
#include <hip/hip_runtime.h>
#include <stdint.h>
#include <stddef.h>

#define BATCH 65536
#define OUTF  1024
#define INF   128

typedef float f32x4 __attribute__((ext_vector_type(4)));
typedef __bf16 bf16x8 __attribute__((ext_vector_type(8)));

#define CPAD 68   // wave-scratch row stride (floats): 64 + 4

// RNE float->bf16, packed pair
__device__ inline uint32_t pack_bf16_rne(float a, float b) {
    uint32_t ua = __builtin_bit_cast(uint32_t, a);
    uint32_t ub = __builtin_bit_cast(uint32_t, b);
    ua += 0x7fffu + ((ua >> 16) & 1u);
    ub += 0x7fffu + ((ub >> 16) & 1u);
    return (ua >> 16) | (ub & 0xffff0000u);
}

// Load 8 contiguous fp32, accumulate sum of squares, return bf16x8 fragment.
__device__ inline bf16x8 load_frag_x2(const float* __restrict__ p, float& s) {
    f32x4 v0 = *(const f32x4*)(p);
    f32x4 v1 = *(const f32x4*)(p + 4);
    s += v0.x * v0.x + v0.y * v0.y + v0.z * v0.z + v0.w * v0.w
       + v1.x * v1.x + v1.y * v1.y + v1.z * v1.z + v1.w * v1.w;
    union { uint32_t u[4]; bf16x8 b; } f;
    f.u[0] = pack_bf16_rne(v0.x, v0.y);
    f.u[1] = pack_bf16_rne(v0.z, v0.w);
    f.u[2] = pack_bf16_rne(v1.x, v1.y);
    f.u[3] = pack_bf16_rne(v1.z, v1.w);
    return f.b;
}

// W prep: one wave per w-row. Writes wb in MFMA FRAGMENT ORDER (R14-verified
// swizzle) + row sumsq. Tile t=row>>4, ks=k>>5, lane wl=((k>>3)&3)*16+(row&15),
// elem j=k&7: addr = ((t*4+ks)*64 + wl)*8 + j. A GEMM B-fragment load is then
// ONE contiguous 1KB instruction.
__global__ __launch_bounds__(256) void wprep_kernel(
        const float* __restrict__ w, float* __restrict__ w2,
        uint32_t* __restrict__ wb) {
    int gtid = blockIdx.x * 256 + threadIdx.x;
    int row  = gtid >> 6;
    int lane = threadIdx.x & 63;
    if (row >= OUTF) return;
    const float* src = w + (size_t)row * INF;
    float2 v = *(const float2*)(src + lane * 2);   // k = 2*lane, 2*lane+1
    int t    = row >> 4;
    int l16r = row & 15;
    int ks   = lane >> 4;
    int lq   = (lane >> 2) & 3;
    int sub  = lane & 3;
    wb[(((size_t)t * 4 + ks) * 64 + lq * 16 + l16r) * 4 + sub] =
        pack_bf16_rne(v.x, v.y);
    float s = v.x * v.x + v.y * v.y;
    #pragma unroll
    for (int off = 32; off; off >>= 1) s += __shfl_down(s, off);
    if (lane == 0) w2[row] = s;
}

// Fused full-width GEMM+epilogue (R9 structure + swizzled B-loads + in-block
// x conversion at 1x redundancy). 512 blocks (2/CU), 4 waves; wave owns
// 32 rows x all 1024 cols in 16 chunks of 64. A-frags built once per block
// from raw fp32 x (no prep pass, no xb HBM bounce); every in-loop B-load is
// one contiguous 1KB instruction from frag-order wb (L2-resident). One
// barrier total; epilogue via wave-private dbuf LDS scratch; NT stores.
__global__ __launch_bounds__(256, 2) void fused_kernel(
        const float* __restrict__ x, const __bf16* __restrict__ wb,
        const float* __restrict__ w2, float* __restrict__ out) {
    int tid  = threadIdx.x;
    int wid  = tid >> 6;
    int lane = tid & 63;
    int l16  = lane & 15;   // fragment row/col
    int lq   = lane >> 4;   // k-quarter (loads) / row-quad (epilogue)

    int row_base = blockIdx.x * 128 + wid * 32;   // this wave's 32 rows

    __shared__ float sw2[OUTF];
    __shared__ float scratch[2][4][32 * CPAD];    // [dbuf][wave][row][col]
    #pragma unroll
    for (int j = 0; j < 4; ++j)
        sw2[tid + 256 * j] = w2[tid + 256 * j];

    // A fragments (2 im x 4 ks, 32 VGPR) + per-row sumsq, converted in-block.
    bf16x8 a[4][2];
    float x2p[2] = {0.f, 0.f};
    #pragma unroll
    for (int ks = 0; ks < 4; ++ks)
        #pragma unroll
        for (int im = 0; im < 2; ++im)
            a[ks][im] = load_frag_x2(
                &x[(size_t)(row_base + im * 16 + l16) * INF + ks * 32 + lq * 8],
                x2p[im]);

    // Row sumsq: butterfly over k-quarter groups; redistribute to epilogue rows.
    #pragma unroll
    for (int im = 0; im < 2; ++im) {
        float s = x2p[im];
        s += __shfl_xor(s, 16);
        s += __shfl_xor(s, 32);
        x2p[im] = s;
    }
    float x2row[2][4];
    #pragma unroll
    for (int im = 0; im < 2; ++im)
        #pragma unroll
        for (int r = 0; r < 4; ++r)
            x2row[im][r] = __shfl(x2p[im], lq * 20 + r);

    __syncthreads();   // sw2 ready — the ONLY barrier

    for (int nc = 0; nc < 16; ++nc) {
        int tb0 = nc * 4;                 // B fragment-tile base for this chunk
        float* buf = scratch[nc & 1][wid];

        f32x4 acc[2][4];
        #pragma unroll
        for (int im = 0; im < 2; ++im)
            #pragma unroll
            for (int in = 0; in < 4; ++in)
                acc[im][in] = f32x4{0.f, 0.f, 0.f, 0.f};

        #pragma unroll
        for (int ks = 0; ks < 4; ++ks) {
            bf16x8 b[4];
            #pragma unroll
            for (int in = 0; in < 4; ++in)
                b[in] = *(const bf16x8*)(
                    (const __bf16*)wb + (((size_t)(tb0 + in) * 4 + ks) << 9) + lane * 8);
            #pragma unroll
            for (int im = 0; im < 2; ++im)
                #pragma unroll
                for (int in = 0; in < 4; ++in)
                    acc[im][in] = __builtin_amdgcn_mfma_f32_16x16x32_bf16(
                        a[ks][im], b[in], acc[im][in], 0, 0, 0);
        }

        // Epilogue math into this wave's private scratch.
        // C/D layout: col = l16, row = lq*4 + r (within each 16x16 fragment).
        #pragma unroll
        for (int im = 0; im < 2; ++im) {
            #pragma unroll
            for (int in = 0; in < 4; ++in) {
                #pragma unroll
                for (int r = 0; r < 4; ++r) {
                    int rloc = im * 16 + lq * 4 + r;              // 0..31
                    int col  = in * 16 + l16;
                    float d2 = x2row[im][r] + sw2[nc * 64 + col] - 2.0f * acc[im][in][r];
                    buf[rloc * CPAD + col] =
                        -0.5f * __builtin_amdgcn_sqrtf(fmaxf(d2, 0.0f));
                }
            }
        }
        // Intra-wave ds_write -> ds_read ordering via lgkmcnt; no barrier.

        // Store this wave's 32 rows x 64 cols: NT f32x4, 256B/row segments.
        #pragma unroll
        for (int k = 0; k < 8; ++k) {
            int row = k * 4 + lq;
            f32x4 v = *(const f32x4*)&buf[row * CPAD + l16 * 4];
            __builtin_nontemporal_store(
                v, (f32x4*)&out[(size_t)(row_base + row) * OUTF + nc * 64 + l16 * 4]);
        }
    }
}

extern "C" void kernel_launch(void* const* d_in, const int* in_sizes, int n_in,
                              void* d_out, int out_size, void* d_ws, size_t ws_size,
                              hipStream_t stream) {
    const float* x = (const float*)d_in[0];
    const float* w = (const float*)d_in[1];
    float* out = (float*)d_out;

    // ws layout: w2 [1024 f32] at 0; wb (frag-order bf16 W, 256KB) at 4096.
    char* ws = (char*)d_ws;
    float* w2 = (float*)ws;
    uint32_t* wb_u32 = (uint32_t*)(ws + 4096);
    const __bf16* wb = (const __bf16*)wb_u32;

    wprep_kernel<<<dim3(OUTF / 4), dim3(256), 0, stream>>>(w, w2, wb_u32);
    fused_kernel<<<dim3(BATCH / 128), dim3(256), 0, stream>>>(x, wb, w2, out);
}

// Round 16
// 80.956 us; speedup vs baseline: 1.1213x; 1.1213x over previous
//
#include <hip/hip_runtime.h>
#include <stdint.h>
#include <stddef.h>

#define BATCH 65536
#define OUTF  1024
#define INF   128

typedef float f32x4 __attribute__((ext_vector_type(4)));
typedef __bf16 bf16x8 __attribute__((ext_vector_type(8)));

#define TSTRIDE 1028  // LDS row stride (floats): 1024 + 4

// RNE float->bf16, packed pair
__device__ inline uint32_t pack_bf16_rne(float a, float b) {
    uint32_t ua = __builtin_bit_cast(uint32_t, a);
    uint32_t ub = __builtin_bit_cast(uint32_t, b);
    ua += 0x7fffu + ((ua >> 16) & 1u);
    ub += 0x7fffu + ((ub >> 16) & 1u);
    return (ua >> 16) | (ub & 0xffff0000u);
}

// Load 8 contiguous fp32, accumulate sum of squares, return bf16x8 fragment.
__device__ inline bf16x8 load_frag_x2(const float* __restrict__ p, float& s) {
    f32x4 v0 = *(const f32x4*)(p);
    f32x4 v1 = *(const f32x4*)(p + 4);
    s += v0.x * v0.x + v0.y * v0.y + v0.z * v0.z + v0.w * v0.w
       + v1.x * v1.x + v1.y * v1.y + v1.z * v1.z + v1.w * v1.w;
    union { uint32_t u[4]; bf16x8 b; } f;
    f.u[0] = pack_bf16_rne(v0.x, v0.y);
    f.u[1] = pack_bf16_rne(v0.z, v0.w);
    f.u[2] = pack_bf16_rne(v1.x, v1.y);
    f.u[3] = pack_bf16_rne(v1.z, v1.w);
    return f.b;
}

// W prep: one wave per w-row. Writes wb in MFMA FRAGMENT ORDER (R14-verified)
// + row sumsq. Tile t=row>>4, ks=k>>5, frag-lane wl=((k>>3)&3)*16+(row&15),
// elem j=k&7: bf16 addr = ((t*4+ks)*64 + wl)*8 + j. A GEMM B-fragment load
// is then ONE contiguous 1KB instruction (base + lane*16B).
__global__ __launch_bounds__(256) void wprep_kernel(
        const float* __restrict__ w, float* __restrict__ w2,
        uint32_t* __restrict__ wb) {
    int gtid = blockIdx.x * 256 + threadIdx.x;
    int row  = gtid >> 6;
    int lane = threadIdx.x & 63;
    if (row >= OUTF) return;
    const float* src = w + (size_t)row * INF;
    float2 v = *(const float2*)(src + lane * 2);   // k = 2*lane, 2*lane+1
    int t    = row >> 4;
    int l16r = row & 15;
    int ks   = lane >> 4;
    int lq   = (lane >> 2) & 3;
    int sub  = lane & 3;
    wb[(((size_t)t * 4 + ks) * 64 + lq * 16 + l16r) * 4 + sub] =
        pack_bf16_rne(v.x, v.y);
    float s = v.x * v.x + v.y * v.y;
    #pragma unroll
    for (int off = 32; off; off >>= 1) s += __shfl_down(s, off);
    if (lane == 0) w2[row] = s;
}

// R10 structure + frag-order wb. Block = 16 x-rows x ALL 1024 cols (4096
// blocks, 2/CU). Output region per block = 64KB FULLY LINEAR; each wave
// stores 4 complete 4KB rows as 1KB instructions. Every B-fragment load is
// ONE contiguous 1KB instruction (vs R10's 16 scattered 64B segments -- the
// suspected cause of its latency-bound 152us). x converted in-block (each
// x-row read by exactly ONE block -> zero cvt redundancy, no xprep pass).
__global__ __launch_bounds__(256, 2) void fused_kernel(
        const float* __restrict__ x, const __bf16* __restrict__ wb,
        const float* __restrict__ w2, float* __restrict__ out) {
    int tid  = threadIdx.x;
    int wid  = tid >> 6;        // wave -> col slice [wid*256, wid*256+256)
    int lane = tid & 63;
    int l16  = lane & 15;       // fragment row/col
    int lq   = lane >> 4;       // k-quarter (loads) / row-quad (epilogue)

    int rbase = blockIdx.x * 16;   // block's 16 x-rows
    int c0    = wid * 256;

    __shared__ float sw2[OUTF];
    __shared__ float tile[16 * TSTRIDE];
    #pragma unroll
    for (int j = 0; j < 4; ++j)
        sw2[tid + 256 * j] = w2[tid + 256 * j];

    // A fragments: 16 rows, k = ks*32 + lq*8. 16 VGPR + x2 partial.
    bf16x8 a[4];
    float x2p = 0.f;
    #pragma unroll
    for (int ks = 0; ks < 4; ++ks)
        a[ks] = load_frag_x2(
            &x[(size_t)(rbase + l16) * INF + ks * 32 + lq * 8], x2p);

    // Row sumsq butterfly over k-quarter groups; redistribute to epilogue rows.
    x2p += __shfl_xor(x2p, 16);
    x2p += __shfl_xor(x2p, 32);
    float x2row[4];
    #pragma unroll
    for (int r = 0; r < 4; ++r)
        x2row[r] = __shfl(x2p, lq * 20 + r);

    // GEMM: 16 rows x 256 cols per wave, K=128. B-frags: 1KB linear insts.
    f32x4 acc[16];
    #pragma unroll
    for (int in = 0; in < 16; ++in)
        acc[in] = f32x4{0.f, 0.f, 0.f, 0.f};

    #pragma unroll
    for (int ks = 0; ks < 4; ++ks) {
        bf16x8 b[16];
        #pragma unroll
        for (int in = 0; in < 16; ++in)
            b[in] = *(const bf16x8*)(
                wb + (((size_t)(wid * 16 + in) * 4 + ks) << 9) + lane * 8);
        #pragma unroll
        for (int in = 0; in < 16; ++in)
            acc[in] = __builtin_amdgcn_mfma_f32_16x16x32_bf16(
                a[ks], b[in], acc[in], 0, 0, 0);
    }

    __syncthreads();   // sw2 ready (no stores outstanding yet)

    // Epilogue into full-width LDS tile (C/D layout: col=l16, row=lq*4+r).
    // Bank pattern per inst: (lq*16 + l16 + const) mod 32 -> 2-way (free).
    #pragma unroll
    for (int in = 0; in < 16; ++in) {
        #pragma unroll
        for (int r = 0; r < 4; ++r) {
            int row = lq * 4 + r;
            int col = c0 + in * 16 + l16;
            float d2 = x2row[r] + sw2[col] - 2.0f * acc[in][r];
            tile[row * TSTRIDE + col] =
                -0.5f * __builtin_amdgcn_sqrtf(fmaxf(d2, 0.0f));
        }
    }
    __syncthreads();   // epilogue visible (still no stores outstanding)

    // Store: wave w owns rows w*4..w*4+3; each 4KB row = 4 consecutive 1KB
    // instructions; block emits one dense 64KB linear span. NT f32x4.
    #pragma unroll
    for (int r = 0; r < 4; ++r) {
        int row = wid * 4 + r;
        size_t gbase = (size_t)(rbase + row) * OUTF;
        #pragma unroll
        for (int q = 0; q < 4; ++q) {
            f32x4 v = *(const f32x4*)&tile[row * TSTRIDE + q * 256 + lane * 4];
            __builtin_nontemporal_store(
                v, (f32x4*)&out[gbase + q * 256 + lane * 4]);
        }
    }
}

extern "C" void kernel_launch(void* const* d_in, const int* in_sizes, int n_in,
                              void* d_out, int out_size, void* d_ws, size_t ws_size,
                              hipStream_t stream) {
    const float* x = (const float*)d_in[0];
    const float* w = (const float*)d_in[1];
    float* out = (float*)d_out;

    // ws layout: w2 [1024 f32] at 0; wb (frag-order bf16 W, 256KB) at 4096.
    char* ws = (char*)d_ws;
    float* w2 = (float*)ws;
    uint32_t* wb_u32 = (uint32_t*)(ws + 4096);
    const __bf16* wb = (const __bf16*)wb_u32;

    wprep_kernel<<<dim3(OUTF / 4), dim3(256), 0, stream>>>(w, w2, wb_u32);
    fused_kernel<<<dim3(BATCH / 16), dim3(256), 0, stream>>>(x, wb, w2, out);
}

// Round 17
// 77.774 us; speedup vs baseline: 1.1672x; 1.0409x over previous
//
#include <hip/hip_runtime.h>
#include <stdint.h>
#include <stddef.h>

#define BATCH 65536
#define OUTF  1024
#define INF   128

typedef float f32x4 __attribute__((ext_vector_type(4)));
typedef __bf16 bf16x8 __attribute__((ext_vector_type(8)));

// RNE float->bf16, packed pair
__device__ inline uint32_t pack_bf16_rne(float a, float b) {
    uint32_t ua = __builtin_bit_cast(uint32_t, a);
    uint32_t ub = __builtin_bit_cast(uint32_t, b);
    ua += 0x7fffu + ((ua >> 16) & 1u);
    ub += 0x7fffu + ((ub >> 16) & 1u);
    return (ua >> 16) | (ub & 0xffff0000u);
}

// Prep: one wave per row. Writes bf16 rows in MFMA FRAGMENT ORDER
// (R14-verified swizzle) + row sum-of-squares.
// Tile t=row>>4, ks=k>>5, frag-lane wl=((k>>3)&3)*16+(row&15), elem j=k&7:
// bf16 addr = ((t*4+ks)*64 + wl)*8 + j -> GEMM fragment load is ONE
// contiguous 1KB instruction.
__global__ __launch_bounds__(256) void prep_kernel(
        const float* __restrict__ x, const float* __restrict__ w,
        float* __restrict__ sumsq, uint32_t* __restrict__ xb,
        uint32_t* __restrict__ wb) {
    int gtid = blockIdx.x * 256 + threadIdx.x;
    int row  = gtid >> 6;
    int lane = threadIdx.x & 63;
    if (row >= BATCH + OUTF) return;
    const float* src;
    uint32_t* dstbase;
    int r;
    if (row < BATCH) {
        src = x + (size_t)row * INF;
        dstbase = xb;
        r = row;
    } else {
        src = w + (size_t)(row - BATCH) * INF;
        dstbase = wb;
        r = row - BATCH;
    }
    float2 v = *(const float2*)(src + lane * 2);   // k = 2*lane, 2*lane+1
    int t    = r >> 4;
    int l16r = r & 15;
    int ks   = lane >> 4;
    int lq   = (lane >> 2) & 3;
    int sub  = lane & 3;
    dstbase[(((size_t)t * 4 + ks) * 64 + lq * 16 + l16r) * 4 + sub] =
        pack_bf16_rne(v.x, v.y);
    float s = v.x * v.x + v.y * v.y;
    #pragma unroll
    for (int off = 32; off; off >>= 1) s += __shfl_down(s, off);
    if (lane == 0) sumsq[row] = s;
}

#define TPAD 132  // LDS chunk row stride (floats)

// 128x128 tile per block, 4 waves (2x2). Frag-order loads (1KB insts) +
// chunked double-buffered epilogue (2 x [32][132] LDS = 34.8KB) ->
// 4 blocks/CU, stores spread across block life in 4 bursts.
__global__ __launch_bounds__(256, 4) void gemm_epi_kernel(
        const __bf16* __restrict__ xb, const __bf16* __restrict__ wb,
        const float* __restrict__ x2, const float* __restrict__ w2,
        float* __restrict__ out) {
    // bijective XCD-chunked swizzle: nwg = 4096 (divisible by 8), nt fastest.
    int bid = blockIdx.x;
    int swz = (bid & 7) * (4096 / 8) + (bid >> 3);
    int mt = swz >> 3;          // 512 m-tiles
    int nt = swz & 7;           // 8 n-tiles
    int m0 = mt * 128, n0 = nt * 128;

    int tid  = threadIdx.x;
    int wid  = tid >> 6;
    int lane = tid & 63;
    int wr = wid >> 1, wc = wid & 1;    // 2x2 wave grid, 64x64 per wave
    int ta = (m0 + wr * 64) >> 4;       // A fragment-tile base
    int tb = (n0 + wc * 64) >> 4;       // B fragment-tile base

    __shared__ float sx2[128];
    __shared__ float sw2[128];
    __shared__ float tile2[2][32 * TPAD];
    if (tid < 128) {
        sx2[tid] = x2[m0 + tid];
        sw2[tid] = w2[n0 + tid];
    }
    __syncthreads();

    int l16 = lane & 15;   // fragment row/col (epilogue)
    int lq  = lane >> 4;   // row-quad selector (epilogue)

    f32x4 acc[4][4];
    #pragma unroll
    for (int i = 0; i < 4; ++i)
        #pragma unroll
        for (int j = 0; j < 4; ++j)
            acc[i][j] = f32x4{0.f, 0.f, 0.f, 0.f};

    #pragma unroll
    for (int ks = 0; ks < 4; ++ks) {
        bf16x8 a[4], b[4];
        #pragma unroll
        for (int im = 0; im < 4; ++im)
            a[im] = *(const bf16x8*)(
                xb + (((size_t)(ta + im) * 4 + ks) << 9) + lane * 8);
        #pragma unroll
        for (int in = 0; in < 4; ++in)
            b[in] = *(const bf16x8*)(
                wb + (((size_t)(tb + in) * 4 + ks) << 9) + lane * 8);
        #pragma unroll
        for (int im = 0; im < 4; ++im)
            #pragma unroll
            for (int in = 0; in < 4; ++in)
                acc[im][in] = __builtin_amdgcn_mfma_f32_16x16x32_bf16(
                    a[im], b[in], acc[im][in], 0, 0, 0);
    }

    // Chunked epilogue: chunk c = tile rows [32c, 32c+32), owned by waves
    // with wr == c>>1 (acc im in {(c&1)*2, (c&1)*2+1}); double-buffered.
    int srow = tid >> 3;          // 0..31  store row within chunk
    int scg  = tid & 7;           // 16B col group base
    #pragma unroll
    for (int c = 0; c < 4; ++c) {
        float* buf = tile2[c & 1];
        if (wr == (c >> 1)) {
            #pragma unroll
            for (int imh = 0; imh < 2; ++imh) {
                int im = (c & 1) * 2 + imh;
                #pragma unroll
                for (int in = 0; in < 4; ++in) {
                    #pragma unroll
                    for (int r = 0; r < 4; ++r) {
                        int row  = wr * 64 + im * 16 + lq * 4 + r;  // tile row
                        int rloc = row - c * 32;                     // 0..31
                        int col  = wc * 64 + in * 16 + l16;
                        float d2 = sx2[row] + sw2[col] - 2.0f * acc[im][in][r];
                        buf[rloc * TPAD + col] =
                            -0.5f * __builtin_amdgcn_sqrtf(fmaxf(d2, 0.0f));
                    }
                }
            }
        }
        __syncthreads();
        // all 256 threads store chunk c: 32 rows x 512B, NT f32x4.
        size_t gbase = (size_t)(m0 + c * 32 + srow) * OUTF + n0;
        #pragma unroll
        for (int j = 0; j < 4; ++j) {
            int col4 = scg + j * 8;
            f32x4 v = *(const f32x4*)&buf[srow * TPAD + col4 * 4];
            __builtin_nontemporal_store(v, (f32x4*)&out[gbase + col4 * 4]);
        }
        // next chunk writes the other buffer; the barrier at the top of the
        // next iteration orders LDS reuse two chunks later.
    }
}

extern "C" void kernel_launch(void* const* d_in, const int* in_sizes, int n_in,
                              void* d_out, int out_size, void* d_ws, size_t ws_size,
                              hipStream_t stream) {
    const float* x = (const float*)d_in[0];
    const float* w = (const float*)d_in[1];
    float* out = (float*)d_out;

    // ws layout: [0, 66560*4) f32 sumsq (x2 then w2);
    // xb (frag-order bf16 x, 16 MiB) at byte 266240; wb after it.
    char* ws = (char*)d_ws;
    float* sumsq = (float*)ws;
    float* x2 = sumsq;
    float* w2 = sumsq + BATCH;
    uint32_t* xb_u32 = (uint32_t*)(ws + 266240);
    uint32_t* wb_u32 = (uint32_t*)(ws + 266240 + (size_t)BATCH * INF * 2);
    const __bf16* xb = (const __bf16*)xb_u32;
    const __bf16* wb = (const __bf16*)wb_u32;

    prep_kernel<<<dim3((BATCH + OUTF) / 4), dim3(256), 0, stream>>>(
        x, w, sumsq, xb_u32, wb_u32);
    gemm_epi_kernel<<<dim3(4096), dim3(256), 0, stream>>>(xb, wb, x2, w2, out);
}